// Round 23
// baseline (63.697 us; speedup 1.0000x reference)
//
#include <hip/hip_runtime.h>
#include <hip/hip_fp16.h>
#include <math.h>

#define NS 64
#define NV 16
#define NHS 32
#define NHV 16
#define NPB 64           // nodes per block in node_pack

// LDS strides (shorts) — conflict-checked: <=2-way on all hot accesses
#define SA 68            // s tile / Ws row stride
#define SV 20            // v tile row stride (16 vv + 4 pad)

// den_scan geometry
#define RANGES 8
#define SPLITS 32
#define DP_STRIDE 50176

typedef __attribute__((ext_vector_type(8))) short short8;
typedef __attribute__((ext_vector_type(4))) float f32x4;
typedef __attribute__((ext_vector_type(4))) unsigned short ushort4v;

__device__ __forceinline__ float silu_f(float x){ return x * (1.0f / (1.0f + __expf(-x))); }

__device__ __forceinline__ float packh2(float a, float b){
    __half2 h = __floats2half2_rn(a, b);
    return __uint_as_float(*(unsigned*)&h);
}
__device__ __forceinline__ float2 unpackh2(float w){
    __half2 h = *(__half2*)&w;
    return __half22float2(h);
}
__device__ __forceinline__ unsigned short f2h(float x){
    return __half_as_ushort(__float2half(x));
}
__device__ __forceinline__ float2 w2f2(unsigned w){
    __half2 h = *(__half2*)&w;
    return __half22float2(h);
}

// fp32 -> bf16 round-to-nearest-even
__device__ __forceinline__ unsigned short f2b(float x){
    unsigned u = __float_as_uint(x);
    unsigned r = (u + 0x7FFFu + ((u >> 16) & 1u)) >> 16;
    return (unsigned short)r;
}

// Per-node precompute: pack[n] = 32B = {A fp32, ff[9]+pos[3] as fp16}
// MFMA + pipelined staging (R22, 61.56us) + LDS DIET (27.6 -> 23.4KB ->
// 6 blocks/CU): strides 72->68 / 24->20, frame/pos stored as fp16-pair
// words whose layout IS the pack payload (store = raw copy).
__global__ __launch_bounds__(256) void node_pack_kernel(
    const float* __restrict__ from_s, const float* __restrict__ from_v,
    const float* __restrict__ from_fr, const float* __restrict__ from_p,
    const float* __restrict__ to_s, const float* __restrict__ to_v,
    const float* __restrict__ to_fr, const float* __restrict__ to_p,
    const float* __restrict__ Wfs, const float* __restrict__ Wts,
    const float* __restrict__ Wfv, const float* __restrict__ Wtv,
    const float* __restrict__ Wattn,
    float* __restrict__ packA, float* __restrict__ packB,
    int N)
{
    const int side = blockIdx.y;
    const float* node_s = side ? to_s  : from_s;
    const float* node_v = side ? to_v  : from_v;
    const float* frame  = side ? to_fr : from_fr;
    const float* pos    = side ? to_p  : from_p;
    const float* Ws     = side ? Wts   : Wfs;
    const float* Wv     = side ? Wtv   : Wfv;
    const int    s_off  = side ? 32 : 0;
    const int    v_off  = side ? 115 : 64;
    float*       pack   = side ? packB : packA;

    __shared__ unsigned short lsA[NPB * SA];      // s tile bf16
    __shared__ unsigned short lsV[3 * NPB * SV];  // v tile bf16 [c][node][vv]
    __shared__ unsigned short lwsB[NHS * SA];     // Ws bf16
    __shared__ unsigned short lwvB[NHV * 20];     // Wv bf16
    __shared__ float lwa[NHS + NHV * 3];          // Wattn slice
    __shared__ unsigned short lfph[NPB * 16];     // fp16: f0..f8,p0..p2 (+pad)
    __shared__ float lacc[NPB];

    const int tid  = threadIdx.x;
    const int lane = tid & 63;
    const int w    = tid >> 6;
    const int nbase = blockIdx.x * NPB;
    const int cnt = min(NPB, N - nbase);

    if (cnt == NPB){
        // ===== FAST PATH: compile-time load counts, loads batch-issued =====
        const float4* wsp = (const float4*)Ws;
        float4 w0 = wsp[tid];
        float4 w1 = wsp[tid + 256];
        float4 wv4; if (tid < 64) wv4 = ((const float4*)Wv)[tid];
        float  wa0; if (tid < NHS) wa0 = Wattn[s_off + tid];
        float  wa1; if (tid < NHV * 3) wa1 = Wattn[v_off + tid];

        const float4* sp = (const float4*)(node_s + (size_t)nbase * NS);
        float4 s0 = sp[tid];
        float4 s1 = sp[tid + 256];
        float4 s2 = sp[tid + 512];
        float4 s3 = sp[tid + 768];

        const float4* vp = (const float4*)(node_v + (size_t)nbase * (NV * 3));
        const int nd = tid >> 2, q = tid & 3;
        float4 vx = vp[nd * 12 + q * 3 + 0];
        float4 vy = vp[nd * 12 + q * 3 + 1];
        float4 vz = vp[nd * 12 + q * 3 + 2];

        const float* fbase = frame + (size_t)nbase * 9;
        float f0 = fbase[tid];
        float f1 = fbase[tid + 256];
        float f2; if (tid < 64) f2 = fbase[tid + 512];
        float p0; if (tid < 192) p0 = pos[(size_t)nbase * 3 + tid];

        // ---- writes (compiler drains vmcnt incrementally) ----
        {
            ushort4v b0 = { f2b(w0.x), f2b(w0.y), f2b(w0.z), f2b(w0.w) };
            *(ushort4v*)(lwsB + (tid >> 4) * SA + (tid & 15) * 4) = b0;
            int i4 = tid + 256;
            ushort4v b1 = { f2b(w1.x), f2b(w1.y), f2b(w1.z), f2b(w1.w) };
            *(ushort4v*)(lwsB + (i4 >> 4) * SA + (i4 & 15) * 4) = b1;
            if (tid < 64){
                ushort4v b = { f2b(wv4.x), f2b(wv4.y), f2b(wv4.z), f2b(wv4.w) };
                *(ushort4v*)(lwvB + (tid >> 2) * 20 + (tid & 3) * 4) = b;
            }
            if (tid < NHS) lwa[tid] = wa0;
            if (tid < NHV * 3) lwa[NHS + tid] = wa1;
        }
        {
            float4 sv[4] = { s0, s1, s2, s3 };
            #pragma unroll
            for (int it = 0; it < 4; it++){
                int i4 = tid + it * 256;
                ushort4v b = { f2b(sv[it].x), f2b(sv[it].y), f2b(sv[it].z), f2b(sv[it].w) };
                *(ushort4v*)(lsA + (i4 >> 4) * SA + (i4 & 15) * 4) = b;
            }
        }
        {
            ushort4v c0 = { f2b(vx.x), f2b(vx.w), f2b(vy.z), f2b(vz.y) };
            ushort4v c1 = { f2b(vx.y), f2b(vy.x), f2b(vy.w), f2b(vz.z) };
            ushort4v c2 = { f2b(vx.z), f2b(vy.y), f2b(vz.x), f2b(vz.w) };
            *(ushort4v*)(lsV + 0 * (NPB * SV) + nd * SV + 4 * q) = c0;
            *(ushort4v*)(lsV + 1 * (NPB * SV) + nd * SV + 4 * q) = c1;
            *(ushort4v*)(lsV + 2 * (NPB * SV) + nd * SV + 4 * q) = c2;
        }
        {
            lfph[(tid / 9) * 16 + (tid % 9)] = f2h(f0);
            int i1 = tid + 256;
            lfph[(i1 / 9) * 16 + (i1 % 9)] = f2h(f1);
            if (tid < 64){
                int i2 = tid + 512;
                lfph[(i2 / 9) * 16 + (i2 % 9)] = f2h(f2);
            }
            if (tid < 192) lfph[(tid / 3) * 16 + 9 + (tid % 3)] = f2h(p0);
        }
    } else {
        // ===== TAIL PATH (1 block): generic loops =====
        const float4* wsp = (const float4*)Ws;
        #pragma unroll
        for (int it = 0; it < 2; it++){
            int i4 = tid + it * 256;
            float4 x = wsp[i4];
            ushort4v b = { f2b(x.x), f2b(x.y), f2b(x.z), f2b(x.w) };
            *(ushort4v*)(lwsB + (i4 >> 4) * SA + (i4 & 15) * 4) = b;
        }
        if (tid < 64){
            float4 x = ((const float4*)Wv)[tid];
            ushort4v b = { f2b(x.x), f2b(x.y), f2b(x.z), f2b(x.w) };
            *(ushort4v*)(lwvB + (tid >> 2) * 20 + (tid & 3) * 4) = b;
        }
        if (tid < NHS) lwa[tid] = Wattn[s_off + tid];
        if (tid < NHV * 3) lwa[NHS + tid] = Wattn[v_off + tid];

        const float4* sp = (const float4*)(node_s + (size_t)nbase * NS);
        for (int i4 = tid; i4 < cnt * 16; i4 += 256){
            float4 x = sp[i4];
            ushort4v b = { f2b(x.x), f2b(x.y), f2b(x.z), f2b(x.w) };
            *(ushort4v*)(lsA + (i4 >> 4) * SA + (i4 & 15) * 4) = b;
        }
        const float4* vp = (const float4*)(node_v + (size_t)nbase * (NV * 3));
        for (int qt = tid; qt < cnt * 4; qt += 256){
            int nd = qt >> 2, q = qt & 3;
            float4 x = vp[nd * 12 + q * 3 + 0];
            float4 y = vp[nd * 12 + q * 3 + 1];
            float4 z = vp[nd * 12 + q * 3 + 2];
            ushort4v c0 = { f2b(x.x), f2b(x.w), f2b(y.z), f2b(z.y) };
            ushort4v c1 = { f2b(x.y), f2b(y.x), f2b(y.w), f2b(z.z) };
            ushort4v c2 = { f2b(x.z), f2b(y.y), f2b(z.x), f2b(z.w) };
            *(ushort4v*)(lsV + 0 * (NPB * SV) + nd * SV + 4 * q) = c0;
            *(ushort4v*)(lsV + 1 * (NPB * SV) + nd * SV + 4 * q) = c1;
            *(ushort4v*)(lsV + 2 * (NPB * SV) + nd * SV + 4 * q) = c2;
        }
        for (int i = tid; i < cnt * 9; i += 256)
            lfph[(i / 9) * 16 + (i % 9)] = f2h(frame[(size_t)nbase * 9 + i]);
        for (int i = tid; i < cnt * 3; i += 256)
            lfph[(i / 3) * 16 + 9 + (i % 3)] = f2h(pos[(size_t)nbase * 3 + i]);
    }
    __syncthreads();

    // ---- B-frags + Wattn from LDS ----
    const int h  = lane & 15;
    const int kq = lane >> 4;
    const int k0 = kq * 8;

    short8 Bs[2][2];
    #pragma unroll
    for (int t = 0; t < 2; t++){
        #pragma unroll
        for (int s = 0; s < 2; s++){
            Bs[t][s] = *(const short8*)(lwsB + (t * 16 + h) * SA + s * 32 + k0);
        }
    }
    short8 Bv = {0,0,0,0,0,0,0,0};
    if (k0 < 16) Bv = *(const short8*)(lwvB + h * 20 + k0);

    const float waS0 = lwa[h];
    const float waS1 = lwa[16 + h];
    const float waV0 = lwa[NHS + h * 3 + 0];
    const float waV1 = lwa[NHS + h * 3 + 1];
    const float waV2 = lwa[NHS + h * 3 + 2];

    // ---- MFMA: this wave's 16 nodes ----
    const int rbase = w * 16;
    const unsigned short* arow = lsA + (rbase + h) * SA;
    short8 A0 = *(const short8*)(arow + k0);
    short8 A1 = *(const short8*)(arow + 32 + k0);
    f32x4 zz = {0.f, 0.f, 0.f, 0.f};
    f32x4 D0 = __builtin_amdgcn_mfma_f32_16x16x32_bf16(A0, Bs[0][0], zz, 0, 0, 0);
    D0       = __builtin_amdgcn_mfma_f32_16x16x32_bf16(A1, Bs[0][1], D0, 0, 0, 0);
    f32x4 D1 = __builtin_amdgcn_mfma_f32_16x16x32_bf16(A0, Bs[1][0], zz, 0, 0, 0);
    D1       = __builtin_amdgcn_mfma_f32_16x16x32_bf16(A1, Bs[1][1], D1, 0, 0, 0);

    short8 zero8 = {0,0,0,0,0,0,0,0};
    f32x4 D2[3];
    #pragma unroll
    for (int c = 0; c < 3; c++){
        short8 Ac = zero8;
        if (k0 < 16)
            Ac = *(const short8*)(lsV + c * (NPB * SV) + (rbase + h) * SV + k0);
        D2[c] = __builtin_amdgcn_mfma_f32_16x16x32_bf16(Ac, Bv, zz, 0, 0, 0);
    }

    // ---- epilogue (frame from fp16 words) ----
    #pragma unroll
    for (int r = 0; r < 4; r++){
        int nl = rbase + kq * 4 + r;
        float d0 = D0[r], d1 = D1[r];
        float a0 = D2[0][r], a1 = D2[1][r], a2 = D2[2][r];
        const unsigned* fw = (const unsigned*)(lfph) + nl * 8;
        float2 q01 = w2f2(fw[0]);
        float2 q23 = w2f2(fw[1]);
        float2 q45 = w2f2(fw[2]);
        float2 q67 = w2f2(fw[3]);
        float2 q8p = w2f2(fw[4]);
        float t0 = a0 * q01.x + a1 * q23.y + a2 * q67.x;
        float t1 = a0 * q01.y + a1 * q45.x + a2 * q67.y;
        float t2 = a0 * q23.x + a1 * q45.y + a2 * q8p.x;
        float contrib = silu_f(d0) * waS0 + silu_f(d1) * waS1
                      + silu_f(t0) * waV0 + silu_f(t1) * waV1 + silu_f(t2) * waV2;
        contrib += __shfl_xor(contrib, 1, 16);
        contrib += __shfl_xor(contrib, 2, 16);
        contrib += __shfl_xor(contrib, 4, 16);
        contrib += __shfl_xor(contrib, 8, 16);
        if (h == 0) lacc[nl] = contrib;
    }
    __syncthreads();

    // ---- pack store: fp16 words are already the pack payload ----
    if (tid < 128){
        int nl = tid >> 1, half = tid & 1;
        if (nl < cnt){
            const unsigned* fw = (const unsigned*)(lfph) + nl * 8;
            float4 o;
            if (half == 0){
                o = make_float4(lacc[nl],
                                __uint_as_float(fw[0]),
                                __uint_as_float(fw[1]),
                                __uint_as_float(fw[2]));
            } else {
                o = make_float4(__uint_as_float(fw[3]),
                                __uint_as_float(fw[4]),
                                __uint_as_float(fw[5]),
                                0.0f);
            }
            ((float4*)(pack + (size_t)(nbase + nl) * 8))[half] = o;
        }
    }
}

// Fused: raw -> exp -> ONE u32/edge: (fp16(ex) << 16) | i0. NO atomics.
__global__ __launch_bounds__(256) void edge_fused_kernel(
    const int* __restrict__ idx,
    const float* __restrict__ packA,
    const float* __restrict__ packB,
    const float* __restrict__ Wattn,
    unsigned* __restrict__ exi,
    int E)
{
    int e = blockIdx.x * 256 + threadIdx.x;
    if (e >= E) return;
    int i0 = __builtin_nontemporal_load(idx + e);
    int i1 = __builtin_nontemporal_load(idx + E + e);
    const float4* pa = (const float4*)(packA + (size_t)i0 * 8);
    const float4* pb = (const float4*)(packB + (size_t)i1 * 8);
    float4 a0 = pa[0], a1 = pa[1];
    float4 b0 = pb[0], b1 = pb[1];

    float2 t;
    t = unpackh2(a0.y); float af0 = t.x, af1 = t.y;
    t = unpackh2(a0.z); float af2 = t.x, af3 = t.y;
    t = unpackh2(a0.w); float af4 = t.x, af5 = t.y;
    t = unpackh2(a1.x); float af6 = t.x, af7 = t.y;
    t = unpackh2(a1.y); float af8 = t.x, ap0 = t.y;
    t = unpackh2(a1.z); float ap1 = t.x, ap2 = t.y;
    t = unpackh2(b0.y); float bf0 = t.x, bf1 = t.y;
    t = unpackh2(b0.z); float bf2 = t.x, bf3 = t.y;
    t = unpackh2(b0.w); float bf4 = t.x, bf5 = t.y;
    t = unpackh2(b1.x); float bf6 = t.x, bf7 = t.y;
    t = unpackh2(b1.y); float bf8 = t.x, bp0 = t.y;
    t = unpackh2(b1.z); float bp1 = t.x, bp2 = t.y;

    float d0 = bp0 - ap0, d1 = bp1 - ap1, d2 = bp2 - ap2;
    float pdf0 = d0*af0 + d1*af3 + d2*af6;
    float pdf1 = d0*af1 + d1*af4 + d2*af7;
    float pdf2 = d0*af2 + d1*af5 + d2*af8;
    float pdt0 = -(d0*bf0 + d1*bf3 + d2*bf6);
    float pdt1 = -(d0*bf1 + d1*bf4 + d2*bf7);
    float pdt2 = -(d0*bf2 + d1*bf5 + d2*bf8);

    float r = a0.x + b0.x;
    r += silu_f(pdf0) * Wattn[112] + silu_f(pdf1) * Wattn[113] + silu_f(pdf2) * Wattn[114];
    r += silu_f(pdt0) * Wattn[163] + silu_f(pdt1) * Wattn[164] + silu_f(pdt2) * Wattn[165];

    float ex = __expf(r);
    unsigned short hx = __half_as_ushort(__float2half(ex));
    __builtin_nontemporal_store(((unsigned)hx << 16) | (unsigned)(i0 & 0xFFFF),
                                exi + e);
}

// Ownership-partitioned segmented sum over the packed (fp16 ex | u16 i0) words.
__global__ __launch_bounds__(512) void den_scan_kernel(
    const unsigned* __restrict__ exi,
    float* __restrict__ den_part,     // [SPLITS][DP_STRIDE]
    int E, int N)
{
    const int s = blockIdx.x & (SPLITS - 1);   // low bits: XCD-affine slice reuse
    const int r = blockIdx.x / SPLITS;
    const int rn = (N + RANGES - 1) / RANGES;
    const int base = r * rn;

    extern __shared__ float lden[];
    for (int i = threadIdx.x; i < rn; i += 512) lden[i] = 0.0f;
    __syncthreads();

    const int es = (E + SPLITS - 1) / SPLITS;
    const int e0 = s * es;
    const int e1 = min(e0 + es, E);

    #pragma unroll 4
    for (int e = e0 + threadIdx.x; e < e1; e += 512){
        unsigned wv = exi[e];
        unsigned d = (wv & 0xFFFFu) - (unsigned)base;
        if (d < (unsigned)rn){
            atomicAdd(&lden[d],
                      __half2float(__ushort_as_half((unsigned short)(wv >> 16))));
        }
    }
    __syncthreads();

    float* dp = den_part + (size_t)s * DP_STRIDE + base;
    for (int i = threadIdx.x; i < rn && base + i < N; i += 512) dp[i] = lden[i];
}

// collapse the SPLITS partial sums; store reciprocal so edge_out multiplies
__global__ __launch_bounds__(256) void collapse_kernel(
    const float* __restrict__ den_part,
    float* __restrict__ inv_den,
    int N)
{
    int i = blockIdx.x * 256 + threadIdx.x;
    if (i >= N) return;
    float sum = 0.f;
    #pragma unroll
    for (int s = 0; s < SPLITS; s++)
        sum += __builtin_nontemporal_load(den_part + (size_t)s * DP_STRIDE + i);
    inv_den[i] = 1.0f / sum;
}

__global__ __launch_bounds__(256) void edge_out_kernel(
    const unsigned* __restrict__ exi,
    const float* __restrict__ inv_den,
    float* __restrict__ out,
    int E)
{
    int e = blockIdx.x * 256 + threadIdx.x;
    if (e >= E) return;
    unsigned wv = __builtin_nontemporal_load(exi + e);
    int i0 = (int)(wv & 0xFFFFu);
    float ex = __half2float(__ushort_as_half((unsigned short)(wv >> 16)));
    __builtin_nontemporal_store(ex * inv_den[i0], out + e);
}

extern "C" void kernel_launch(void* const* d_in, const int* in_sizes, int n_in,
                              void* d_out, int out_size, void* d_ws, size_t ws_size,
                              hipStream_t stream)
{
    const float* from_s  = (const float*)d_in[0];
    const float* from_v  = (const float*)d_in[1];
    const float* to_s    = (const float*)d_in[2];
    const float* to_v    = (const float*)d_in[3];
    const float* from_fr = (const float*)d_in[4];
    const float* to_fr   = (const float*)d_in[5];
    const float* from_p  = (const float*)d_in[6];
    const float* to_p    = (const float*)d_in[7];
    const float* Wfs     = (const float*)d_in[8];
    const float* Wts     = (const float*)d_in[9];
    const float* Wfv     = (const float*)d_in[10];
    const float* Wtv     = (const float*)d_in[11];
    const float* Wattn   = (const float*)d_in[12];
    const int*   idx     = (const int*)d_in[13];

    int N = in_sizes[0] / NS;
    int E = in_sizes[13] / 2;
    float* out = (float*)d_out;

    char* ws = (char*)d_ws;
    size_t packBytes = (size_t)N * 8 * sizeof(float);
    float*    packA    = (float*)(ws);
    float*    packB    = (float*)(ws + packBytes);
    unsigned* exi      = (unsigned*)(ws + 2 * packBytes);
    float*    den_part = (float*)(ws + 2 * packBytes + (size_t)E * 4);
    float*    inv_den  = (float*)(ws + 2 * packBytes + (size_t)E * 4
                                   + (size_t)SPLITS * DP_STRIDE * 4);

    dim3 ngrid((N + NPB - 1) / NPB, 2);
    node_pack_kernel<<<ngrid, 256, 0, stream>>>(
        from_s, from_v, from_fr, from_p,
        to_s, to_v, to_fr, to_p,
        Wfs, Wts, Wfv, Wtv, Wattn,
        packA, packB, N);

    int nb_e = (E + 255) / 256;
    edge_fused_kernel<<<nb_e, 256, 0, stream>>>(idx, packA, packB, Wattn, exi, E);

    int rn = (N + RANGES - 1) / RANGES;
    size_t lds_bytes = (size_t)rn * sizeof(float);
    den_scan_kernel<<<RANGES * SPLITS, 512, lds_bytes, stream>>>(exi, den_part, E, N);
    collapse_kernel<<<(N + 255) / 256, 256, 0, stream>>>(den_part, inv_den, N);
    edge_out_kernel<<<nb_e, 256, 0, stream>>>(exi, inv_den, out, E);
}

// Round 24
// 61.382 us; speedup vs baseline: 1.0377x; 1.0377x over previous
//
#include <hip/hip_runtime.h>
#include <hip/hip_fp16.h>
#include <math.h>

#define NS 64
#define NV 16
#define NHS 32
#define NHV 16
#define NPB 64           // nodes per block in node_pack

// den_scan geometry
#define RANGES 8
#define SPLITS 32
#define DP_STRIDE 50176

typedef __attribute__((ext_vector_type(8))) short short8;
typedef __attribute__((ext_vector_type(4))) float f32x4;
typedef __attribute__((ext_vector_type(4))) unsigned short ushort4v;

__device__ __forceinline__ float silu_f(float x){ return x * (1.0f / (1.0f + __expf(-x))); }

__device__ __forceinline__ float packh2(float a, float b){
    __half2 h = __floats2half2_rn(a, b);
    return __uint_as_float(*(unsigned*)&h);
}
__device__ __forceinline__ float2 unpackh2(float w){
    __half2 h = *(__half2*)&w;
    return __half22float2(h);
}

// fp32 -> bf16 round-to-nearest-even
__device__ __forceinline__ unsigned short f2b(float x){
    unsigned u = __float_as_uint(x);
    unsigned r = (u + 0x7FFFu + ((u >> 16) & 1u)) >> 16;
    return (unsigned short)r;
}

// Per-node precompute: pack[n] = 32B = {A fp32, ff[9]+pos[3] as fp16}
// MFMA (benched best, 61.56us): block = 4 waves x 64 nodes; full blocks take
// a straight-line staging path with compile-time load counts (loads
// batch-issued, one incremental vmcnt drain); scalar GEMV = 4 mfma
// 16x16x32_bf16, vector GEMV = 3 mfma (K zero-padded 16->32, channel-split v).
__global__ __launch_bounds__(256) void node_pack_kernel(
    const float* __restrict__ from_s, const float* __restrict__ from_v,
    const float* __restrict__ from_fr, const float* __restrict__ from_p,
    const float* __restrict__ to_s, const float* __restrict__ to_v,
    const float* __restrict__ to_fr, const float* __restrict__ to_p,
    const float* __restrict__ Wfs, const float* __restrict__ Wts,
    const float* __restrict__ Wfv, const float* __restrict__ Wtv,
    const float* __restrict__ Wattn,
    float* __restrict__ packA, float* __restrict__ packB,
    int N)
{
    const int side = blockIdx.y;
    const float* node_s = side ? to_s  : from_s;
    const float* node_v = side ? to_v  : from_v;
    const float* frame  = side ? to_fr : from_fr;
    const float* pos    = side ? to_p  : from_p;
    const float* Ws     = side ? Wts   : Wfs;
    const float* Wv     = side ? Wtv   : Wfv;
    const int    s_off  = side ? 32 : 0;
    const int    v_off  = side ? 115 : 64;
    float*       pack   = side ? packB : packA;

    __shared__ unsigned short lsA[NPB * 72];      // s tile bf16, stride 72
    __shared__ unsigned short lsV[3 * NPB * 24];  // v tile bf16 [c][node][vv]
    __shared__ unsigned short lwsB[NHS * 72];     // Ws bf16, stride 72
    __shared__ unsigned short lwvB[NHV * 20];     // Wv bf16, stride 20
    __shared__ float lwa[NHS + NHV * 3];          // Wattn slice
    __shared__ float lfp[NPB * 13];               // frame(9)+pos(3)
    __shared__ float lacc[NPB];

    const int tid  = threadIdx.x;
    const int lane = tid & 63;
    const int w    = tid >> 6;
    const int nbase = blockIdx.x * NPB;
    const int cnt = min(NPB, N - nbase);

    if (cnt == NPB){
        // ===== FAST PATH: all load counts compile-time; loads batch-issued =====
        const float4* wsp = (const float4*)Ws;
        float4 w0 = wsp[tid];
        float4 w1 = wsp[tid + 256];
        float4 wv4; if (tid < 64) wv4 = ((const float4*)Wv)[tid];
        float  wa0; if (tid < NHS) wa0 = Wattn[s_off + tid];
        float  wa1; if (tid < NHV * 3) wa1 = Wattn[v_off + tid];

        const float4* sp = (const float4*)(node_s + (size_t)nbase * NS);
        float4 s0 = sp[tid];
        float4 s1 = sp[tid + 256];
        float4 s2 = sp[tid + 512];
        float4 s3 = sp[tid + 768];

        const float4* vp = (const float4*)(node_v + (size_t)nbase * (NV * 3));
        const int nd = tid >> 2, q = tid & 3;      // tid == nd*4+q, cnt*4 == 256
        float4 vx = vp[nd * 12 + q * 3 + 0];
        float4 vy = vp[nd * 12 + q * 3 + 1];
        float4 vz = vp[nd * 12 + q * 3 + 2];

        const float* fbase = frame + (size_t)nbase * 9;
        float f0 = fbase[tid];
        float f1 = fbase[tid + 256];
        float f2; if (tid < 64) f2 = fbase[tid + 512];
        float p0; if (tid < 192) p0 = pos[(size_t)nbase * 3 + tid];

        // ---- writes (compiler drains vmcnt incrementally) ----
        {
            ushort4v b0 = { f2b(w0.x), f2b(w0.y), f2b(w0.z), f2b(w0.w) };
            *(ushort4v*)(lwsB + (tid >> 4) * 72 + (tid & 15) * 4) = b0;
            int i4 = tid + 256;
            ushort4v b1 = { f2b(w1.x), f2b(w1.y), f2b(w1.z), f2b(w1.w) };
            *(ushort4v*)(lwsB + (i4 >> 4) * 72 + (i4 & 15) * 4) = b1;
            if (tid < 64){
                ushort4v b = { f2b(wv4.x), f2b(wv4.y), f2b(wv4.z), f2b(wv4.w) };
                *(ushort4v*)(lwvB + (tid >> 2) * 20 + (tid & 3) * 4) = b;
            }
            if (tid < NHS) lwa[tid] = wa0;
            if (tid < NHV * 3) lwa[NHS + tid] = wa1;
        }
        {
            float4 sv[4] = { s0, s1, s2, s3 };
            #pragma unroll
            for (int it = 0; it < 4; it++){
                int i4 = tid + it * 256;
                ushort4v b = { f2b(sv[it].x), f2b(sv[it].y), f2b(sv[it].z), f2b(sv[it].w) };
                *(ushort4v*)(lsA + (i4 >> 4) * 72 + (i4 & 15) * 4) = b;
            }
        }
        {
            ushort4v c0 = { f2b(vx.x), f2b(vx.w), f2b(vy.z), f2b(vz.y) };
            ushort4v c1 = { f2b(vx.y), f2b(vy.x), f2b(vy.w), f2b(vz.z) };
            ushort4v c2 = { f2b(vx.z), f2b(vy.y), f2b(vz.x), f2b(vz.w) };
            *(ushort4v*)(lsV + 0 * (NPB * 24) + nd * 24 + 4 * q) = c0;
            *(ushort4v*)(lsV + 1 * (NPB * 24) + nd * 24 + 4 * q) = c1;
            *(ushort4v*)(lsV + 2 * (NPB * 24) + nd * 24 + 4 * q) = c2;
        }
        {
            lfp[(tid / 9) * 13 + (tid % 9)] = f0;
            int i1 = tid + 256;
            lfp[(i1 / 9) * 13 + (i1 % 9)] = f1;
            if (tid < 64){
                int i2 = tid + 512;
                lfp[(i2 / 9) * 13 + (i2 % 9)] = f2;
            }
            if (tid < 192) lfp[(tid / 3) * 13 + 9 + (tid % 3)] = p0;
        }
    } else {
        // ===== TAIL PATH (1 block): generic loops =====
        const float4* wsp = (const float4*)Ws;
        #pragma unroll
        for (int it = 0; it < 2; it++){
            int i4 = tid + it * 256;
            float4 x = wsp[i4];
            ushort4v b = { f2b(x.x), f2b(x.y), f2b(x.z), f2b(x.w) };
            *(ushort4v*)(lwsB + (i4 >> 4) * 72 + (i4 & 15) * 4) = b;
        }
        if (tid < 64){
            float4 x = ((const float4*)Wv)[tid];
            ushort4v b = { f2b(x.x), f2b(x.y), f2b(x.z), f2b(x.w) };
            *(ushort4v*)(lwvB + (tid >> 2) * 20 + (tid & 3) * 4) = b;
        }
        if (tid < NHS) lwa[tid] = Wattn[s_off + tid];
        if (tid < NHV * 3) lwa[NHS + tid] = Wattn[v_off + tid];

        const float4* sp = (const float4*)(node_s + (size_t)nbase * NS);
        for (int i4 = tid; i4 < cnt * 16; i4 += 256){
            float4 x = sp[i4];
            ushort4v b = { f2b(x.x), f2b(x.y), f2b(x.z), f2b(x.w) };
            *(ushort4v*)(lsA + (i4 >> 4) * 72 + (i4 & 15) * 4) = b;
        }
        const float4* vp = (const float4*)(node_v + (size_t)nbase * (NV * 3));
        for (int qt = tid; qt < cnt * 4; qt += 256){
            int nd = qt >> 2, q = qt & 3;
            float4 x = vp[nd * 12 + q * 3 + 0];
            float4 y = vp[nd * 12 + q * 3 + 1];
            float4 z = vp[nd * 12 + q * 3 + 2];
            ushort4v c0 = { f2b(x.x), f2b(x.w), f2b(y.z), f2b(z.y) };
            ushort4v c1 = { f2b(x.y), f2b(y.x), f2b(y.w), f2b(z.z) };
            ushort4v c2 = { f2b(x.z), f2b(y.y), f2b(z.x), f2b(z.w) };
            *(ushort4v*)(lsV + 0 * (NPB * 24) + nd * 24 + 4 * q) = c0;
            *(ushort4v*)(lsV + 1 * (NPB * 24) + nd * 24 + 4 * q) = c1;
            *(ushort4v*)(lsV + 2 * (NPB * 24) + nd * 24 + 4 * q) = c2;
        }
        for (int i = tid; i < cnt * 9; i += 256)
            lfp[(i / 9) * 13 + (i % 9)] = frame[(size_t)nbase * 9 + i];
        for (int i = tid; i < cnt * 3; i += 256)
            lfp[(i / 3) * 13 + 9 + (i % 3)] = pos[(size_t)nbase * 3 + i];
    }
    __syncthreads();

    // ---- B-frags + Wattn from LDS ----
    const int h  = lane & 15;
    const int kq = lane >> 4;
    const int k0 = kq * 8;

    short8 Bs[2][2];
    #pragma unroll
    for (int t = 0; t < 2; t++){
        #pragma unroll
        for (int s = 0; s < 2; s++){
            Bs[t][s] = *(const short8*)(lwsB + (t * 16 + h) * 72 + s * 32 + k0);
        }
    }
    short8 Bv = {0,0,0,0,0,0,0,0};
    if (k0 < 16) Bv = *(const short8*)(lwvB + h * 20 + k0);

    const float waS0 = lwa[h];
    const float waS1 = lwa[16 + h];
    const float waV0 = lwa[NHS + h * 3 + 0];
    const float waV1 = lwa[NHS + h * 3 + 1];
    const float waV2 = lwa[NHS + h * 3 + 2];

    // ---- MFMA: this wave's 16 nodes ----
    const int rbase = w * 16;
    const unsigned short* arow = lsA + (rbase + h) * 72;
    short8 A0 = *(const short8*)(arow + k0);
    short8 A1 = *(const short8*)(arow + 32 + k0);
    f32x4 zz = {0.f, 0.f, 0.f, 0.f};
    f32x4 D0 = __builtin_amdgcn_mfma_f32_16x16x32_bf16(A0, Bs[0][0], zz, 0, 0, 0);
    D0       = __builtin_amdgcn_mfma_f32_16x16x32_bf16(A1, Bs[0][1], D0, 0, 0, 0);
    f32x4 D1 = __builtin_amdgcn_mfma_f32_16x16x32_bf16(A0, Bs[1][0], zz, 0, 0, 0);
    D1       = __builtin_amdgcn_mfma_f32_16x16x32_bf16(A1, Bs[1][1], D1, 0, 0, 0);

    short8 zero8 = {0,0,0,0,0,0,0,0};
    f32x4 D2[3];
    #pragma unroll
    for (int c = 0; c < 3; c++){
        short8 Ac = zero8;
        if (k0 < 16)
            Ac = *(const short8*)(lsV + c * (NPB * 24) + (rbase + h) * 24 + k0);
        D2[c] = __builtin_amdgcn_mfma_f32_16x16x32_bf16(Ac, Bv, zz, 0, 0, 0);
    }

    // ---- epilogue ----
    #pragma unroll
    for (int r = 0; r < 4; r++){
        int nl = rbase + kq * 4 + r;
        float d0 = D0[r], d1 = D1[r];
        float a0 = D2[0][r], a1 = D2[1][r], a2 = D2[2][r];
        const float* fb = lfp + nl * 13;
        float t0 = a0 * fb[0] + a1 * fb[3] + a2 * fb[6];
        float t1 = a0 * fb[1] + a1 * fb[4] + a2 * fb[7];
        float t2 = a0 * fb[2] + a1 * fb[5] + a2 * fb[8];
        float contrib = silu_f(d0) * waS0 + silu_f(d1) * waS1
                      + silu_f(t0) * waV0 + silu_f(t1) * waV1 + silu_f(t2) * waV2;
        contrib += __shfl_xor(contrib, 1, 16);
        contrib += __shfl_xor(contrib, 2, 16);
        contrib += __shfl_xor(contrib, 4, 16);
        contrib += __shfl_xor(contrib, 8, 16);
        if (h == 0) lacc[nl] = contrib;
    }
    __syncthreads();

    // ---- pack store: 2 threads per node, fully coalesced ----
    if (tid < 128){
        int nl = tid >> 1, half = tid & 1;
        if (nl < cnt){
            const float* fb = lfp + nl * 13;
            float4 o;
            if (half == 0){
                o = make_float4(lacc[nl],
                                packh2(fb[0], fb[1]),
                                packh2(fb[2], fb[3]),
                                packh2(fb[4], fb[5]));
            } else {
                o = make_float4(packh2(fb[6], fb[7]),
                                packh2(fb[8], fb[9]),
                                packh2(fb[10], fb[11]),
                                0.0f);
            }
            ((float4*)(pack + (size_t)(nbase + nl) * 8))[half] = o;
        }
    }
}

// Fused: raw -> exp -> ONE u32/edge: (fp16(ex) << 16) | i0. NO atomics.
__global__ __launch_bounds__(256) void edge_fused_kernel(
    const int* __restrict__ idx,
    const float* __restrict__ packA,
    const float* __restrict__ packB,
    const float* __restrict__ Wattn,
    unsigned* __restrict__ exi,
    int E)
{
    int e = blockIdx.x * 256 + threadIdx.x;
    if (e >= E) return;
    int i0 = __builtin_nontemporal_load(idx + e);
    int i1 = __builtin_nontemporal_load(idx + E + e);
    const float4* pa = (const float4*)(packA + (size_t)i0 * 8);
    const float4* pb = (const float4*)(packB + (size_t)i1 * 8);
    float4 a0 = pa[0], a1 = pa[1];
    float4 b0 = pb[0], b1 = pb[1];

    float2 t;
    t = unpackh2(a0.y); float af0 = t.x, af1 = t.y;
    t = unpackh2(a0.z); float af2 = t.x, af3 = t.y;
    t = unpackh2(a0.w); float af4 = t.x, af5 = t.y;
    t = unpackh2(a1.x); float af6 = t.x, af7 = t.y;
    t = unpackh2(a1.y); float af8 = t.x, ap0 = t.y;
    t = unpackh2(a1.z); float ap1 = t.x, ap2 = t.y;
    t = unpackh2(b0.y); float bf0 = t.x, bf1 = t.y;
    t = unpackh2(b0.z); float bf2 = t.x, bf3 = t.y;
    t = unpackh2(b0.w); float bf4 = t.x, bf5 = t.y;
    t = unpackh2(b1.x); float bf6 = t.x, bf7 = t.y;
    t = unpackh2(b1.y); float bf8 = t.x, bp0 = t.y;
    t = unpackh2(b1.z); float bp1 = t.x, bp2 = t.y;

    float d0 = bp0 - ap0, d1 = bp1 - ap1, d2 = bp2 - ap2;
    float pdf0 = d0*af0 + d1*af3 + d2*af6;
    float pdf1 = d0*af1 + d1*af4 + d2*af7;
    float pdf2 = d0*af2 + d1*af5 + d2*af8;
    float pdt0 = -(d0*bf0 + d1*bf3 + d2*bf6);
    float pdt1 = -(d0*bf1 + d1*bf4 + d2*bf7);
    float pdt2 = -(d0*bf2 + d1*bf5 + d2*bf8);

    float r = a0.x + b0.x;
    r += silu_f(pdf0) * Wattn[112] + silu_f(pdf1) * Wattn[113] + silu_f(pdf2) * Wattn[114];
    r += silu_f(pdt0) * Wattn[163] + silu_f(pdt1) * Wattn[164] + silu_f(pdt2) * Wattn[165];

    float ex = __expf(r);
    unsigned short hx = __half_as_ushort(__float2half(ex));
    __builtin_nontemporal_store(((unsigned)hx << 16) | (unsigned)(i0 & 0xFFFF),
                                exi + e);
}

// Ownership-partitioned segmented sum over the packed (fp16 ex | u16 i0) words.
__global__ __launch_bounds__(512) void den_scan_kernel(
    const unsigned* __restrict__ exi,
    float* __restrict__ den_part,     // [SPLITS][DP_STRIDE]
    int E, int N)
{
    const int s = blockIdx.x & (SPLITS - 1);   // low bits: XCD-affine slice reuse
    const int r = blockIdx.x / SPLITS;
    const int rn = (N + RANGES - 1) / RANGES;
    const int base = r * rn;

    extern __shared__ float lden[];
    for (int i = threadIdx.x; i < rn; i += 512) lden[i] = 0.0f;
    __syncthreads();

    const int es = (E + SPLITS - 1) / SPLITS;
    const int e0 = s * es;
    const int e1 = min(e0 + es, E);

    #pragma unroll 4
    for (int e = e0 + threadIdx.x; e < e1; e += 512){
        unsigned wv = exi[e];
        unsigned d = (wv & 0xFFFFu) - (unsigned)base;
        if (d < (unsigned)rn){
            atomicAdd(&lden[d],
                      __half2float(__ushort_as_half((unsigned short)(wv >> 16))));
        }
    }
    __syncthreads();

    float* dp = den_part + (size_t)s * DP_STRIDE + base;
    for (int i = threadIdx.x; i < rn && base + i < N; i += 512) dp[i] = lden[i];
}

// collapse the SPLITS partial sums; store reciprocal so edge_out multiplies
__global__ __launch_bounds__(256) void collapse_kernel(
    const float* __restrict__ den_part,
    float* __restrict__ inv_den,
    int N)
{
    int i = blockIdx.x * 256 + threadIdx.x;
    if (i >= N) return;
    float sum = 0.f;
    #pragma unroll
    for (int s = 0; s < SPLITS; s++)
        sum += __builtin_nontemporal_load(den_part + (size_t)s * DP_STRIDE + i);
    inv_den[i] = 1.0f / sum;
}

__global__ __launch_bounds__(256) void edge_out_kernel(
    const unsigned* __restrict__ exi,
    const float* __restrict__ inv_den,
    float* __restrict__ out,
    int E)
{
    int e = blockIdx.x * 256 + threadIdx.x;
    if (e >= E) return;
    unsigned wv = __builtin_nontemporal_load(exi + e);
    int i0 = (int)(wv & 0xFFFFu);
    float ex = __half2float(__ushort_as_half((unsigned short)(wv >> 16)));
    __builtin_nontemporal_store(ex * inv_den[i0], out + e);
}

extern "C" void kernel_launch(void* const* d_in, const int* in_sizes, int n_in,
                              void* d_out, int out_size, void* d_ws, size_t ws_size,
                              hipStream_t stream)
{
    const float* from_s  = (const float*)d_in[0];
    const float* from_v  = (const float*)d_in[1];
    const float* to_s    = (const float*)d_in[2];
    const float* to_v    = (const float*)d_in[3];
    const float* from_fr = (const float*)d_in[4];
    const float* to_fr   = (const float*)d_in[5];
    const float* from_p  = (const float*)d_in[6];
    const float* to_p    = (const float*)d_in[7];
    const float* Wfs     = (const float*)d_in[8];
    const float* Wts     = (const float*)d_in[9];
    const float* Wfv     = (const float*)d_in[10];
    const float* Wtv     = (const float*)d_in[11];
    const float* Wattn   = (const float*)d_in[12];
    const int*   idx     = (const int*)d_in[13];

    int N = in_sizes[0] / NS;
    int E = in_sizes[13] / 2;
    float* out = (float*)d_out;

    char* ws = (char*)d_ws;
    size_t packBytes = (size_t)N * 8 * sizeof(float);
    float*    packA    = (float*)(ws);
    float*    packB    = (float*)(ws + packBytes);
    unsigned* exi      = (unsigned*)(ws + 2 * packBytes);
    float*    den_part = (float*)(ws + 2 * packBytes + (size_t)E * 4);
    float*    inv_den  = (float*)(ws + 2 * packBytes + (size_t)E * 4
                                   + (size_t)SPLITS * DP_STRIDE * 4);

    dim3 ngrid((N + NPB - 1) / NPB, 2);
    node_pack_kernel<<<ngrid, 256, 0, stream>>>(
        from_s, from_v, from_fr, from_p,
        to_s, to_v, to_fr, to_p,
        Wfs, Wts, Wfv, Wtv, Wattn,
        packA, packB, N);

    int nb_e = (E + 255) / 256;
    edge_fused_kernel<<<nb_e, 256, 0, stream>>>(idx, packA, packB, Wattn, exi, E);

    int rn = (N + RANGES - 1) / RANGES;
    size_t lds_bytes = (size_t)rn * sizeof(float);
    den_scan_kernel<<<RANGES * SPLITS, 512, lds_bytes, stream>>>(exi, den_part, E, N);
    collapse_kernel<<<(N + 255) / 256, 256, 0, stream>>>(den_part, inv_den, N);
    edge_out_kernel<<<nb_e, 256, 0, stream>>>(exi, inv_den, out, E);
}